// Round 11
// baseline (387.109 us; speedup 1.0000x reference)
//
#include <hip/hip_runtime.h>
#include <math.h>

#define HEADS 4
#define DIM 32
#define FDIM 128   // HEADS*DIM
#define EPB 8192   // edges per binning block
#define BPBSH 8    // 256 nodes per coarse bucket
#define WB 16      // convw blocks per relation (fused into binA grid)

typedef __attribute__((ext_vector_type(8))) short short8;
typedef __attribute__((ext_vector_type(16))) float float16;

__device__ __forceinline__ unsigned short f2bf(float x) {
  unsigned u = __float_as_uint(x);
  u += 0x7FFFu + ((u >> 16) & 1);   // round-to-nearest-even
  return (unsigned short)(u >> 16);
}

// ---------------- pass A1: per-block coarse histogram (+fused W->bf16^T) ----------
// cntA layout: [r][bucket][blk] (bucket-major -> scanA reads contiguous)
__global__ __launch_bounds__(256) void binA_kernel(const int* __restrict__ edges,
    int* __restrict__ cntA, const float* __restrict__ W1, const float* __restrict__ W2,
    unsigned short* __restrict__ WT, int E, int BA, int BAp, int R) {
  int r = blockIdx.y, blk = blockIdx.x, t = threadIdx.x;
  if (blk >= BA) {   // convw tail blocks: convert W1[r],W2[r] -> WT transposed bf16
    int wb = blk - BA;
    int base = wb * (32768 / WB);
#pragma unroll
    for (int j = 0; j < 32768 / WB; j += 256) {
      int idx = base + j + t;          // 0..32767 within relation r
      int layer = idx >> 14;
      int rem = idx & 16383;
      int n = rem >> 7, k = rem & 127;
      const float* W = layer ? (W2 + (size_t)r * FDIM * FDIM)
                             : (W1 + (size_t)r * FDIM * FDIM);
      WT[((size_t)(layer * R + r) << 14) + rem] = f2bf(W[k * FDIM + n]);
    }
    return;
  }
  __shared__ int hist[256];
  hist[t] = 0;
  __syncthreads();
  const int* dst = edges + (size_t)r * 2 * E + E;
  int base = blk * EPB;
#pragma unroll
  for (int j = 0; j < EPB / 256; ++j) {
    int e = base + t + j * 256;
    if (e < E) atomicAdd(&hist[dst[e] >> BPBSH], 1);
  }
  __syncthreads();
  cntA[((size_t)r * 256 + t) * BAp + blk] = hist[t];
}

// ---------------- pass A2: bucket bases + per-block cursors (parallel) -------------
__global__ __launch_bounds__(256) void scanA_kernel(int* __restrict__ cntA,
    int* __restrict__ bucketBase, int E, int NB, int BA, int BAp) {
  __shared__ int stot[256];
  int r = blockIdx.x, b = threadIdx.x;
  int* row = cntA + ((size_t)r * 256 + b) * BAp;
  int tot = 0;
  if (b < NB)
    for (int blk = 0; blk < BA; ++blk) tot += row[blk];   // independent stride-1 loads
  stot[b] = tot;
  __syncthreads();
  for (int ofs = 1; ofs < 256; ofs <<= 1) {               // Hillis-Steele inclusive
    int u = (b >= ofs) ? stot[b - ofs] : 0;
    __syncthreads();
    stot[b] += u;
    __syncthreads();
  }
  int excl = stot[b] - tot;
  if (b < NB) bucketBase[r * 257 + b] = excl;
  if (b == 0) bucketBase[r * 257 + NB] = E;
  if (b < NB) {
    int run = excl;
    for (int blk = 0; blk < BA; ++blk) {                  // L2-hot re-read
      int c = row[blk];
      row[blk] = run;
      run += c;
    }
  }
}

// ---------------- pass A3: scatter (dst,src) into coarse-bucket regions ------------
__global__ __launch_bounds__(256) void scatterA_kernel(const int* __restrict__ edges,
    const int* __restrict__ cntA, int2* __restrict__ binned, int E, int BA, int BAp) {
  __shared__ int cur[256];
  int r = blockIdx.y, blk = blockIdx.x, t = threadIdx.x;
  cur[t] = cntA[((size_t)r * 256 + t) * BAp + blk];
  __syncthreads();
  const int* srcp = edges + (size_t)r * 2 * E;
  const int* dstp = srcp + E;
  int2* bout = binned + (size_t)r * E;
  int base = blk * EPB;
#pragma unroll
  for (int j = 0; j < EPB / 256; ++j) {
    int e = base + t + j * 256;
    if (e < E) {
      int d = dstp[e], s = srcp[e];
      int pos = atomicAdd(&cur[d >> BPBSH], 1);
      bout[pos] = make_int2(d, s);
    }
  }
}

// ---------------- pass B: exact per-node CSR within each bucket --------------------
__global__ __launch_bounds__(256) void passB_kernel(const int2* __restrict__ binned,
    const int* __restrict__ bucketBase, int* __restrict__ csr, int* __restrict__ indptr,
    int E, int N, int NB) {
  __shared__ int cnt[256];
  __shared__ int off[256];
  __shared__ int cur[256];
  int r = blockIdx.y, b = blockIdx.x, t = threadIdx.x;
  int beg = bucketBase[r * 257 + b];
  int end = bucketBase[r * 257 + b + 1];
  cnt[t] = 0;
  __syncthreads();
  const int2* bin = binned + (size_t)r * E;
  for (int i = beg + t; i < end; i += 256)
    atomicAdd(&cnt[bin[i].x & 255], 1);
  __syncthreads();
  for (int ofs = 1; ofs < 256; ofs <<= 1) {
    int u = (t >= ofs) ? cnt[t - ofs] : 0;
    __syncthreads();
    cnt[t] += u;
    __syncthreads();
  }
  int ex = beg + ((t > 0) ? cnt[t - 1] : 0);
  off[t] = ex;
  cur[t] = ex;
  __syncthreads();
  int node = b * 256 + t;
  if (node < N) indptr[(size_t)r * (N + 1) + node] = off[t];
  if (b == NB - 1 && t == 0) indptr[(size_t)r * (N + 1) + N] = E;
  int* csr_r = csr + (size_t)r * E;
  for (int i = beg + t; i < end; i += 256) {
    int2 p = bin[i];
    int rank = atomicAdd(&cur[p.x & 255], 1);
    csr_r[rank] = p.y;
  }
}

// ---------------- MFMA matmul + fused coef, LDS-tiled epilogue (R8-proven) --------
__global__ __launch_bounds__(256) void mm_kernel(const float* __restrict__ A,
    const unsigned short* __restrict__ WTl, const float* __restrict__ al_all,
    const float* __restrict__ ar_all, unsigned short* __restrict__ featb_all,
    float* __restrict__ el_all, float* __restrict__ er_all, int N) {
  __shared__ unsigned short sA[128 * 136];
  __shared__ float sAl[FDIM], sAr[FDIM];
  int r = blockIdx.y;
  const unsigned short* WT = WTl + (size_t)r * FDIM * FDIM;
  int row0 = blockIdx.x * 128;
  int t = threadIdx.x;
  if (t < FDIM) {
    sAl[t] = al_all[r * FDIM + t];
    sAr[t] = ar_all[r * FDIM + t];
  }
#pragma unroll
  for (int it = 0; it < 16; ++it) {
    int idx = t * 4 + it * 1024;
    int row = idx >> 7, k = idx & 127;
    int grow = row0 + row;
    float4 v = make_float4(0.f, 0.f, 0.f, 0.f);
    if (grow < N) v = *(const float4*)(A + (size_t)grow * FDIM + k);
    unsigned short* p = sA + row * 136 + k;
    p[0] = f2bf(v.x); p[1] = f2bf(v.y); p[2] = f2bf(v.z); p[3] = f2bf(v.w);
  }
  __syncthreads();
  int lane = t & 63, w = t >> 6;
  int m = lane & 31, q = lane >> 5;
  float16 acc[4] = {0.f, 0.f, 0.f, 0.f};
#pragma unroll
  for (int kc = 0; kc < 8; ++kc) {
    int ko = kc * 16 + q * 8;
    short8 a = *(const short8*)(sA + (w * 32 + m) * 136 + ko);
#pragma unroll
    for (int nt = 0; nt < 4; ++nt) {
      short8 bb = *(const short8*)(WT + (size_t)(nt * 32 + m) * FDIM + ko);
      acc[nt] = __builtin_amdgcn_mfma_f32_32x32x16_bf16(a, bb, acc[nt], 0, 0, 0);
    }
  }
  __syncthreads();
#pragma unroll
  for (int nt = 0; nt < 4; ++nt) {
#pragma unroll
    for (int reg = 0; reg < 16; ++reg) {
      int rr = (reg & 3) + 8 * (reg >> 2) + 4 * q;   // C-layout (m74/m101)
      sA[(w * 32 + rr) * 136 + nt * 32 + m] = f2bf(acc[nt][reg]);
    }
  }
  __syncthreads();
  unsigned short* fb = featb_all + (size_t)r * N * FDIM;
#pragma unroll
  for (int it = 0; it < 8; ++it) {
    int idx = (t + it * 256) * 8;
    int row = idx >> 7, k = idx & 127;
    int grow = row0 + row;
    if (grow < N)
      *(uint4*)(fb + (size_t)grow * FDIM + k) = *(const uint4*)(sA + row * 136 + k);
  }
  int rowc = t >> 1, grow = row0 + rowc;
  if (grow < N) {
    float* elr = el_all + (size_t)r * N * 4;
    float* err_ = er_all + (size_t)r * N * 4;
#pragma unroll
    for (int hh = 0; hh < 2; ++hh) {
      int hd = (t & 1) * 2 + hh;
      const uint4* rp4 = (const uint4*)(sA + rowc * 136 + hd * DIM);
      const float4* alp = (const float4*)(sAl + hd * DIM);
      const float4* arp = (const float4*)(sAr + hd * DIM);
      float sl = 0.f, sr = 0.f;
#pragma unroll
      for (int gq = 0; gq < 4; ++gq) {
        uint4 u = rp4[gq];
        float4 a0 = alp[2 * gq], a1 = alp[2 * gq + 1];
        float4 r0 = arp[2 * gq], r1 = arp[2 * gq + 1];
        unsigned uv[4] = {u.x, u.y, u.z, u.w};
        float fv[8];
#pragma unroll
        for (int j = 0; j < 4; ++j) {
          fv[2 * j] = __uint_as_float(uv[j] << 16);
          fv[2 * j + 1] = __uint_as_float(uv[j] & 0xFFFF0000u);
        }
        sl = fmaf(fv[0], a0.x, sl); sr = fmaf(fv[0], r0.x, sr);
        sl = fmaf(fv[1], a0.y, sl); sr = fmaf(fv[1], r0.y, sr);
        sl = fmaf(fv[2], a0.z, sl); sr = fmaf(fv[2], r0.z, sr);
        sl = fmaf(fv[3], a0.w, sl); sr = fmaf(fv[3], r0.w, sr);
        sl = fmaf(fv[4], a1.x, sl); sr = fmaf(fv[4], r1.x, sr);
        sl = fmaf(fv[5], a1.y, sl); sr = fmaf(fv[5], r1.y, sr);
        sl = fmaf(fv[6], a1.z, sl); sr = fmaf(fv[6], r1.z, sr);
        sl = fmaf(fv[7], a1.w, sl); sr = fmaf(fv[7], r1.w, sr);
      }
      elr[(size_t)grow * 4 + hd] = sl;
      err_[(size_t)grow * 4 + hd] = sr;
    }
  }
}

// ---------------- layer-1 aggregation (CSR; 16 threads/node = 4 heads x 4 strides) -
__global__ __launch_bounds__(256) void agg1_kernel(const unsigned short* __restrict__ featb,
    const float* __restrict__ el, const float* __restrict__ er,
    const int* __restrict__ indptr, const int* __restrict__ csr,
    const float* __restrict__ bias, float* __restrict__ hout, int N, int E, int R) {
  int t = blockIdx.x * 256 + threadIdx.x;
  int node = t >> 4;
  if (node >= N) return;
  int hd = t & 3, sub = (t >> 2) & 3;
  float tot[32];
#pragma unroll
  for (int i = 0; i < 32; ++i) tot[i] = 0.f;
  for (int r = 0; r < R; ++r) {
    const unsigned short* f = featb + (size_t)r * N * FDIM + hd * DIM;
    const float* elr = el + (size_t)r * N * 4;
    const int* csr_r = csr + (size_t)r * E;
    const int* ip = indptr + (size_t)r * (N + 1);
    float er_h = er[(size_t)r * N * 4 + node * 4 + hd];
    int beg = ip[node], end = ip[node + 1];
    float l = 0.f, a[32];
#pragma unroll
    for (int i = 0; i < 32; ++i) a[i] = 0.f;
    for (int i = beg + sub; i < end; i += 4) {
      int s = csr_r[i];
      float ee = elr[s * 4 + hd] + er_h;
      ee = ee > 0.f ? ee : 0.2f * ee;        // LeakyReLU
      float p = __expf(ee);                  // no max-sub: pre-activations tame
      const uint4* fp = (const uint4*)(f + (size_t)s * FDIM);
      uint4 u0 = fp[0], u1 = fp[1], u2 = fp[2], u3 = fp[3];
      l += p;
      unsigned uu[16] = {u0.x, u0.y, u0.z, u0.w, u1.x, u1.y, u1.z, u1.w,
                         u2.x, u2.y, u2.z, u2.w, u3.x, u3.y, u3.z, u3.w};
#pragma unroll
      for (int j = 0; j < 16; ++j) {
        float f0 = __uint_as_float(uu[j] << 16);
        float f1 = __uint_as_float(uu[j] & 0xFFFF0000u);
        a[2 * j]     = fmaf(p, f0, a[2 * j]);
        a[2 * j + 1] = fmaf(p, f1, a[2 * j + 1]);
      }
    }
    l += __shfl_xor(l, 4);                   // merge 4 strides
    l += __shfl_xor(l, 8);
#pragma unroll
    for (int i = 0; i < 32; ++i) {
      float v = a[i];
      v += __shfl_xor(v, 4);
      v += __shfl_xor(v, 8);
      a[i] = v;
    }
    float inv = (l > 0.f) ? 1.f / l : 0.f;
    const float4* b4 = (const float4*)(bias + r * FDIM + hd * DIM);
#pragma unroll
    for (int g = 0; g < 8; ++g) {
      float4 bv = b4[g];
      float v0 = a[4 * g] * inv + bv.x;
      float v1 = a[4 * g + 1] * inv + bv.y;
      float v2 = a[4 * g + 2] * inv + bv.z;
      float v3 = a[4 * g + 3] * inv + bv.w;
      tot[4 * g]     += v0 > 0.f ? v0 : __expf(v0) - 1.f;   // ELU
      tot[4 * g + 1] += v1 > 0.f ? v1 : __expf(v1) - 1.f;
      tot[4 * g + 2] += v2 > 0.f ? v2 : __expf(v2) - 1.f;
      tot[4 * g + 3] += v3 > 0.f ? v3 : __expf(v3) - 1.f;
    }
  }
  if (sub == 0) {
    float4* hp = (float4*)(hout + (size_t)node * FDIM + hd * DIM);
#pragma unroll
    for (int g = 0; g < 8; ++g)
      hp[g] = make_float4(tot[4 * g], tot[4 * g + 1], tot[4 * g + 2], tot[4 * g + 3]);
  }
}

// ---------------- layer-2 aggregation + residual + bias + head-mean ----------------
__global__ __launch_bounds__(256) void agg2_kernel(const unsigned short* __restrict__ featb,
    const float* __restrict__ el, const float* __restrict__ er,
    const int* __restrict__ indptr, const int* __restrict__ csr,
    const float* __restrict__ bias, const float* __restrict__ hf,
    float* __restrict__ out, int N, int E, int R) {
  int t = blockIdx.x * 256 + threadIdx.x;
  int node = t >> 4;
  if (node >= N) return;
  int hd = t & 3, sub = (t >> 2) & 3;
  float tot[32];
#pragma unroll
  for (int i = 0; i < 32; ++i) tot[i] = 0.f;
  for (int r = 0; r < R; ++r) {
    const unsigned short* f = featb + (size_t)r * N * FDIM + hd * DIM;
    const float* elr = el + (size_t)r * N * 4;
    const int* csr_r = csr + (size_t)r * E;
    const int* ip = indptr + (size_t)r * (N + 1);
    float er_h = er[(size_t)r * N * 4 + node * 4 + hd];
    int beg = ip[node], end = ip[node + 1];
    float l = 0.f, a[32];
#pragma unroll
    for (int i = 0; i < 32; ++i) a[i] = 0.f;
    for (int i = beg + sub; i < end; i += 4) {
      int s = csr_r[i];
      float ee = elr[s * 4 + hd] + er_h;
      ee = ee > 0.f ? ee : 0.2f * ee;
      float p = __expf(ee);
      const uint4* fp = (const uint4*)(f + (size_t)s * FDIM);
      uint4 u0 = fp[0], u1 = fp[1], u2 = fp[2], u3 = fp[3];
      l += p;
      unsigned uu[16] = {u0.x, u0.y, u0.z, u0.w, u1.x, u1.y, u1.z, u1.w,
                         u2.x, u2.y, u2.z, u2.w, u3.x, u3.y, u3.z, u3.w};
#pragma unroll
      for (int j = 0; j < 16; ++j) {
        float f0 = __uint_as_float(uu[j] << 16);
        float f1 = __uint_as_float(uu[j] & 0xFFFF0000u);
        a[2 * j]     = fmaf(p, f0, a[2 * j]);
        a[2 * j + 1] = fmaf(p, f1, a[2 * j + 1]);
      }
    }
    l += __shfl_xor(l, 4);
    l += __shfl_xor(l, 8);
#pragma unroll
    for (int i = 0; i < 32; ++i) {
      float v = a[i];
      v += __shfl_xor(v, 4);
      v += __shfl_xor(v, 8);
      a[i] = v;
    }
    float inv = (l > 0.f) ? 1.f / l : 0.f;
    const float4* b4 = (const float4*)(bias + r * FDIM + hd * DIM);
#pragma unroll
    for (int g = 0; g < 8; ++g) {
      float4 bv = b4[g];
      tot[4 * g]     += a[4 * g] * inv + bv.x;
      tot[4 * g + 1] += a[4 * g + 1] * inv + bv.y;
      tot[4 * g + 2] += a[4 * g + 2] * inv + bv.z;
      tot[4 * g + 3] += a[4 * g + 3] * inv + bv.w;
    }
  }
  {
    const float4* rv4 = (const float4*)(hf + (size_t)node * FDIM + hd * DIM);
#pragma unroll
    for (int g = 0; g < 8; ++g) {
      float4 rv = rv4[g];
      tot[4 * g]     += R * rv.x;
      tot[4 * g + 1] += R * rv.y;
      tot[4 * g + 2] += R * rv.z;
      tot[4 * g + 3] += R * rv.w;
    }
  }
#pragma unroll
  for (int i = 0; i < 32; ++i) {
    float v = tot[i];
    v += __shfl_xor(v, 1);
    v += __shfl_xor(v, 2);
    tot[i] = v * 0.25f;
  }
  if (sub == 0) {
    float4* op = (float4*)(out + (size_t)node * 32 + hd * 8);
    op[0] = make_float4(tot[hd * 8], tot[hd * 8 + 1], tot[hd * 8 + 2], tot[hd * 8 + 3]);
    op[1] = make_float4(tot[hd * 8 + 4], tot[hd * 8 + 5], tot[hd * 8 + 6], tot[hd * 8 + 7]);
  }
}

extern "C" void kernel_launch(void* const* d_in, const int* in_sizes, int n_in,
                              void* d_out, int out_size, void* d_ws, size_t ws_size,
                              hipStream_t stream) {
  const float* x   = (const float*)d_in[0];
  const float* W1  = (const float*)d_in[1];
  const float* al1 = (const float*)d_in[2];
  const float* ar1 = (const float*)d_in[3];
  const float* b1  = (const float*)d_in[4];
  const float* W2  = (const float*)d_in[5];
  const float* al2 = (const float*)d_in[6];
  const float* ar2 = (const float*)d_in[7];
  const float* b2  = (const float*)d_in[8];
  const int* edges = (const int*)d_in[9];
  float* out = (float*)d_out;

  const int N = in_sizes[0] / FDIM;          // 50000
  const int R = in_sizes[1] / (FDIM * FDIM); // 2
  const int E = in_sizes[9] / (2 * R);       // 800000
  const int BA = (E + EPB - 1) / EPB;        // binning blocks per relation
  const int BAp = (BA + 3) & ~3;             // padded for int4-friendly rows
  const int NB = (N + 255) >> BPBSH;         // coarse buckets (<=256)

  char* ws = (char*)d_ws;
  size_t off = 0;
  auto alloc = [&](size_t bytes) {
    char* p = ws + off;
    off += (bytes + 255) & ~(size_t)255;
    return p;
  };
  unsigned short* featb = (unsigned short*)alloc((size_t)R * N * FDIM * 2);  // 25.6 MB
  unsigned short* WT    = (unsigned short*)alloc((size_t)2 * R * FDIM * FDIM * 2);
  float* el = (float*)alloc((size_t)R * N * 4 * 4);
  float* er = (float*)alloc((size_t)R * N * 4 * 4);
  float* h  = (float*)alloc((size_t)N * FDIM * 4);
  int* cntA = (int*)alloc((size_t)R * 256 * BAp * 4);
  int* bucketBase = (int*)alloc((size_t)R * 257 * 4);
  int2* binned = (int2*)alloc((size_t)R * E * 8);          // 12.8 MB
  int* csr = (int*)alloc((size_t)R * E * 4);               // 6.4 MB
  int* indptr = (int*)alloc((size_t)R * (N + 1) * 4);

  // ---- CSR build (LDS atomics only) + fused W conversion ----
  dim3 bgrid(BA + WB, R);
  binA_kernel<<<bgrid, 256, 0, stream>>>(edges, cntA, W1, W2, WT, E, BA, BAp, R);
  scanA_kernel<<<R, 256, 0, stream>>>(cntA, bucketBase, E, NB, BA, BAp);
  dim3 sgrid(BA, R);
  scatterA_kernel<<<sgrid, 256, 0, stream>>>(edges, cntA, binned, E, BA, BAp);
  dim3 pgrid(NB, R);
  passB_kernel<<<pgrid, 256, 0, stream>>>(binned, bucketBase, csr, indptr, E, N, NB);

  dim3 mmgrid((N + 127) / 128, R);
  int agrid = (N * 16 + 255) / 256;

  // ---- layer 1 ----
  mm_kernel<<<mmgrid, 256, 0, stream>>>(x, WT, al1, ar1, featb, el, er, N);
  agg1_kernel<<<agrid, 256, 0, stream>>>(featb, el, er, indptr, csr, b1, h, N, E, R);

  // ---- layer 2 ----
  mm_kernel<<<mmgrid, 256, 0, stream>>>(h, WT + (size_t)R * FDIM * FDIM, al2, ar2, featb, el, er, N);
  agg2_kernel<<<agrid, 256, 0, stream>>>(featb, el, er, indptr, csr, b2, h, out, N, E, R);
}

// Round 13
// 369.454 us; speedup vs baseline: 1.0478x; 1.0478x over previous
//
#include <hip/hip_runtime.h>
#include <math.h>

#define HEADS 4
#define DIM 32
#define FDIM 128   // HEADS*DIM
#define EPB 8192   // edges per binning block
#define BPBSH 8    // 256 nodes per coarse bucket
#define WB 16      // convw blocks per relation (fused into binA grid)

typedef __attribute__((ext_vector_type(8))) short short8;
typedef __attribute__((ext_vector_type(16))) float float16;

__device__ __forceinline__ unsigned short f2bf(float x) {
  unsigned u = __float_as_uint(x);
  u += 0x7FFFu + ((u >> 16) & 1);   // round-to-nearest-even
  return (unsigned short)(u >> 16);
}

// ---------------- pass A1: per-block coarse histogram (+fused W->bf16^T) ----------
// cntA layout: [r][bucket][blk] (bucket-major -> scanA reads contiguous)
__global__ __launch_bounds__(256) void binA_kernel(const int* __restrict__ edges,
    int* __restrict__ cntA, const float* __restrict__ W1, const float* __restrict__ W2,
    unsigned short* __restrict__ WT, int E, int BA, int BAp, int R) {
  int r = blockIdx.y, blk = blockIdx.x, t = threadIdx.x;
  if (blk >= BA) {   // convw tail blocks
    int wb = blk - BA;
    int base = wb * (32768 / WB);
#pragma unroll
    for (int j = 0; j < 32768 / WB; j += 256) {
      int idx = base + j + t;
      int layer = idx >> 14;
      int rem = idx & 16383;
      int n = rem >> 7, k = rem & 127;
      const float* W = layer ? (W2 + (size_t)r * FDIM * FDIM)
                             : (W1 + (size_t)r * FDIM * FDIM);
      WT[((size_t)(layer * R + r) << 14) + rem] = f2bf(W[k * FDIM + n]);
    }
    return;
  }
  __shared__ int hist[256];
  hist[t] = 0;
  __syncthreads();
  const int* dst = edges + (size_t)r * 2 * E + E;
  int base = blk * EPB;
#pragma unroll
  for (int j = 0; j < EPB / 256; ++j) {
    int e = base + t + j * 256;
    if (e < E) atomicAdd(&hist[dst[e] >> BPBSH], 1);
  }
  __syncthreads();
  cntA[((size_t)r * 256 + t) * BAp + blk] = hist[t];
}

// ---------------- pass A2: bucket bases + per-block cursors (parallel) -------------
__global__ __launch_bounds__(256) void scanA_kernel(int* __restrict__ cntA,
    int* __restrict__ bucketBase, int E, int NB, int BA, int BAp) {
  __shared__ int stot[256];
  int r = blockIdx.x, b = threadIdx.x;
  int* row = cntA + ((size_t)r * 256 + b) * BAp;
  int tot = 0;
  if (b < NB)
    for (int blk = 0; blk < BA; ++blk) tot += row[blk];
  stot[b] = tot;
  __syncthreads();
  for (int ofs = 1; ofs < 256; ofs <<= 1) {
    int u = (b >= ofs) ? stot[b - ofs] : 0;
    __syncthreads();
    stot[b] += u;
    __syncthreads();
  }
  int excl = stot[b] - tot;
  if (b < NB) bucketBase[r * 257 + b] = excl;
  if (b == 0) bucketBase[r * 257 + NB] = E;
  if (b < NB) {
    int run = excl;
    for (int blk = 0; blk < BA; ++blk) {
      int c = row[blk];
      row[blk] = run;
      run += c;
    }
  }
}

// ---------------- pass A3: scatter packed (dst<<16)|src into bucket regions -------
// N < 65536 so both ids fit 16 bits: 4B/edge instead of 8B.
__global__ __launch_bounds__(256) void scatterA_kernel(const int* __restrict__ edges,
    const int* __restrict__ cntA, unsigned* __restrict__ binned, int E, int BA, int BAp) {
  __shared__ int cur[256];
  int r = blockIdx.y, blk = blockIdx.x, t = threadIdx.x;
  cur[t] = cntA[((size_t)r * 256 + t) * BAp + blk];
  __syncthreads();
  const int* srcp = edges + (size_t)r * 2 * E;
  const int* dstp = srcp + E;
  unsigned* bout = binned + (size_t)r * E;
  int base = blk * EPB;
#pragma unroll
  for (int j = 0; j < EPB / 256; ++j) {
    int e = base + t + j * 256;
    if (e < E) {
      int d = dstp[e], s = srcp[e];
      int pos = atomicAdd(&cur[d >> BPBSH], 1);
      bout[pos] = ((unsigned)d << 16) | (unsigned)s;
    }
  }
}

// ---------------- pass B: exact per-node CSR within each bucket --------------------
__global__ __launch_bounds__(256) void passB_kernel(const unsigned* __restrict__ binned,
    const int* __restrict__ bucketBase, int* __restrict__ csr, int* __restrict__ indptr,
    int E, int N, int NB) {
  __shared__ int cnt[256];
  __shared__ int off[256];
  __shared__ int cur[256];
  int r = blockIdx.y, b = blockIdx.x, t = threadIdx.x;
  int beg = bucketBase[r * 257 + b];
  int end = bucketBase[r * 257 + b + 1];
  cnt[t] = 0;
  __syncthreads();
  const unsigned* bin = binned + (size_t)r * E;
  for (int i = beg + t; i < end; i += 256)
    atomicAdd(&cnt[(bin[i] >> 16) & 255], 1);
  __syncthreads();
  for (int ofs = 1; ofs < 256; ofs <<= 1) {
    int u = (t >= ofs) ? cnt[t - ofs] : 0;
    __syncthreads();
    cnt[t] += u;
    __syncthreads();
  }
  int ex = beg + ((t > 0) ? cnt[t - 1] : 0);
  off[t] = ex;
  cur[t] = ex;
  __syncthreads();
  int node = b * 256 + t;
  if (node < N) indptr[(size_t)r * (N + 1) + node] = off[t];
  if (b == NB - 1 && t == 0) indptr[(size_t)r * (N + 1) + N] = E;
  int* csr_r = csr + (size_t)r * E;
  for (int i = beg + t; i < end; i += 256) {
    unsigned p = bin[i];
    int rank = atomicAdd(&cur[(p >> 16) & 255], 1);
    csr_r[rank] = (int)(p & 0xFFFFu);
  }
}

// ---------------- MFMA matmul + fused coef, LDS-tiled epilogue (R8/R11-proven) ----
__global__ __launch_bounds__(256) void mm_kernel(const float* __restrict__ A,
    const unsigned short* __restrict__ WTl, const float* __restrict__ al_all,
    const float* __restrict__ ar_all, unsigned short* __restrict__ featb_all,
    float* __restrict__ el_all, float* __restrict__ er_all, int N) {
  __shared__ unsigned short sA[128 * 136];
  __shared__ float sAl[FDIM], sAr[FDIM];
  int r = blockIdx.y;
  const unsigned short* WT = WTl + (size_t)r * FDIM * FDIM;
  int row0 = blockIdx.x * 128;
  int t = threadIdx.x;
  if (t < FDIM) {
    sAl[t] = al_all[r * FDIM + t];
    sAr[t] = ar_all[r * FDIM + t];
  }
#pragma unroll
  for (int it = 0; it < 16; ++it) {
    int idx = t * 4 + it * 1024;
    int row = idx >> 7, k = idx & 127;
    int grow = row0 + row;
    float4 v = make_float4(0.f, 0.f, 0.f, 0.f);
    if (grow < N) v = *(const float4*)(A + (size_t)grow * FDIM + k);
    unsigned short* p = sA + row * 136 + k;
    p[0] = f2bf(v.x); p[1] = f2bf(v.y); p[2] = f2bf(v.z); p[3] = f2bf(v.w);
  }
  __syncthreads();
  int lane = t & 63, w = t >> 6;
  int m = lane & 31, q = lane >> 5;
  float16 acc[4] = {0.f, 0.f, 0.f, 0.f};
#pragma unroll
  for (int kc = 0; kc < 8; ++kc) {
    int ko = kc * 16 + q * 8;
    short8 a = *(const short8*)(sA + (w * 32 + m) * 136 + ko);
#pragma unroll
    for (int nt = 0; nt < 4; ++nt) {
      short8 bb = *(const short8*)(WT + (size_t)(nt * 32 + m) * FDIM + ko);
      acc[nt] = __builtin_amdgcn_mfma_f32_32x32x16_bf16(a, bb, acc[nt], 0, 0, 0);
    }
  }
  __syncthreads();
#pragma unroll
  for (int nt = 0; nt < 4; ++nt) {
#pragma unroll
    for (int reg = 0; reg < 16; ++reg) {
      int rr = (reg & 3) + 8 * (reg >> 2) + 4 * q;   // C-layout (m74/m101)
      sA[(w * 32 + rr) * 136 + nt * 32 + m] = f2bf(acc[nt][reg]);
    }
  }
  __syncthreads();
  unsigned short* fb = featb_all + (size_t)r * N * FDIM;
#pragma unroll
  for (int it = 0; it < 8; ++it) {
    int idx = (t + it * 256) * 8;
    int row = idx >> 7, k = idx & 127;
    int grow = row0 + row;
    if (grow < N)
      *(uint4*)(fb + (size_t)grow * FDIM + k) = *(const uint4*)(sA + row * 136 + k);
  }
  int rowc = t >> 1, grow = row0 + rowc;
  if (grow < N) {
    float* elr = el_all + (size_t)r * N * 4;
    float* err_ = er_all + (size_t)r * N * 4;
#pragma unroll
    for (int hh = 0; hh < 2; ++hh) {
      int hd = (t & 1) * 2 + hh;
      const uint4* rp4 = (const uint4*)(sA + rowc * 136 + hd * DIM);
      const float4* alp = (const float4*)(sAl + hd * DIM);
      const float4* arp = (const float4*)(sAr + hd * DIM);
      float sl = 0.f, sr = 0.f;
#pragma unroll
      for (int gq = 0; gq < 4; ++gq) {
        uint4 u = rp4[gq];
        float4 a0 = alp[2 * gq], a1 = alp[2 * gq + 1];
        float4 r0 = arp[2 * gq], r1 = arp[2 * gq + 1];
        unsigned uv[4] = {u.x, u.y, u.z, u.w};
        float fv[8];
#pragma unroll
        for (int j = 0; j < 4; ++j) {
          fv[2 * j] = __uint_as_float(uv[j] << 16);
          fv[2 * j + 1] = __uint_as_float(uv[j] & 0xFFFF0000u);
        }
        sl = fmaf(fv[0], a0.x, sl); sr = fmaf(fv[0], r0.x, sr);
        sl = fmaf(fv[1], a0.y, sl); sr = fmaf(fv[1], r0.y, sr);
        sl = fmaf(fv[2], a0.z, sl); sr = fmaf(fv[2], r0.z, sr);
        sl = fmaf(fv[3], a0.w, sl); sr = fmaf(fv[3], r0.w, sr);
        sl = fmaf(fv[4], a1.x, sl); sr = fmaf(fv[4], r1.x, sr);
        sl = fmaf(fv[5], a1.y, sl); sr = fmaf(fv[5], r1.y, sr);
        sl = fmaf(fv[6], a1.z, sl); sr = fmaf(fv[6], r1.z, sr);
        sl = fmaf(fv[7], a1.w, sl); sr = fmaf(fv[7], r1.w, sr);
      }
      elr[(size_t)grow * 4 + hd] = sl;
      err_[(size_t)grow * 4 + hd] = sr;
    }
  }
}

// ---------------- layer-1 aggregation (exact R10-proven form) ----------------------
__global__ __launch_bounds__(256) void agg1_kernel(const unsigned short* __restrict__ featb,
    const float* __restrict__ el, const float* __restrict__ er,
    const int* __restrict__ indptr, const int* __restrict__ csr,
    const float* __restrict__ bias, float* __restrict__ hout, int N, int E, int R) {
  int t = blockIdx.x * 256 + threadIdx.x;
  int node = t >> 3;
  if (node >= N) return;
  int hd = t & 3, sub = (t >> 2) & 1;
  float tot[32];
#pragma unroll
  for (int i = 0; i < 32; ++i) tot[i] = 0.f;
  for (int r = 0; r < R; ++r) {
    const unsigned short* f = featb + (size_t)r * N * FDIM + hd * DIM;
    const float* elr = el + (size_t)r * N * 4;
    const int* csr_r = csr + (size_t)r * E;
    const int* ip = indptr + (size_t)r * (N + 1);
    float er_h = er[(size_t)r * N * 4 + node * 4 + hd];
    int beg = ip[node], end = ip[node + 1];
    float l = 0.f, a[32];
#pragma unroll
    for (int i = 0; i < 32; ++i) a[i] = 0.f;
    for (int i = beg + sub; i < end; i += 2) {
      int s = csr_r[i];
      float ee = elr[s * 4 + hd] + er_h;
      ee = ee > 0.f ? ee : 0.2f * ee;        // LeakyReLU
      float p = __expf(ee);                  // no max-sub: pre-activations tame
      const uint4* fp = (const uint4*)(f + (size_t)s * FDIM);
      uint4 u0 = fp[0], u1 = fp[1], u2 = fp[2], u3 = fp[3];
      l += p;
      unsigned uu[16] = {u0.x, u0.y, u0.z, u0.w, u1.x, u1.y, u1.z, u1.w,
                         u2.x, u2.y, u2.z, u2.w, u3.x, u3.y, u3.z, u3.w};
#pragma unroll
      for (int j = 0; j < 16; ++j) {
        float f0 = __uint_as_float(uu[j] << 16);
        float f1 = __uint_as_float(uu[j] & 0xFFFF0000u);
        a[2 * j]     = fmaf(p, f0, a[2 * j]);
        a[2 * j + 1] = fmaf(p, f1, a[2 * j + 1]);
      }
    }
    l += __shfl_xor(l, 4);                   // merge even/odd strides
#pragma unroll
    for (int i = 0; i < 32; ++i) a[i] += __shfl_xor(a[i], 4);
    float inv = (l > 0.f) ? 1.f / l : 0.f;
    const float4* b4 = (const float4*)(bias + r * FDIM + hd * DIM);
#pragma unroll
    for (int g = 0; g < 8; ++g) {
      float4 bv = b4[g];
      float v0 = a[4 * g] * inv + bv.x;
      float v1 = a[4 * g + 1] * inv + bv.y;
      float v2 = a[4 * g + 2] * inv + bv.z;
      float v3 = a[4 * g + 3] * inv + bv.w;
      tot[4 * g]     += v0 > 0.f ? v0 : __expf(v0) - 1.f;   // ELU
      tot[4 * g + 1] += v1 > 0.f ? v1 : __expf(v1) - 1.f;
      tot[4 * g + 2] += v2 > 0.f ? v2 : __expf(v2) - 1.f;
      tot[4 * g + 3] += v3 > 0.f ? v3 : __expf(v3) - 1.f;
    }
  }
  if (sub == 0) {
    float4* hp = (float4*)(hout + (size_t)node * FDIM + hd * DIM);
#pragma unroll
    for (int g = 0; g < 8; ++g)
      hp[g] = make_float4(tot[4 * g], tot[4 * g + 1], tot[4 * g + 2], tot[4 * g + 3]);
  }
}

// ---------------- layer-2 aggregation + residual + bias + head-mean ----------------
__global__ __launch_bounds__(256) void agg2_kernel(const unsigned short* __restrict__ featb,
    const float* __restrict__ el, const float* __restrict__ er,
    const int* __restrict__ indptr, const int* __restrict__ csr,
    const float* __restrict__ bias, const float* __restrict__ hf,
    float* __restrict__ out, int N, int E, int R) {
  int t = blockIdx.x * 256 + threadIdx.x;
  int node = t >> 3;
  if (node >= N) return;
  int hd = t & 3, sub = (t >> 2) & 1;
  float tot[32];
#pragma unroll
  for (int i = 0; i < 32; ++i) tot[i] = 0.f;
  for (int r = 0; r < R; ++r) {
    const unsigned short* f = featb + (size_t)r * N * FDIM + hd * DIM;
    const float* elr = el + (size_t)r * N * 4;
    const int* csr_r = csr + (size_t)r * E;
    const int* ip = indptr + (size_t)r * (N + 1);
    float er_h = er[(size_t)r * N * 4 + node * 4 + hd];
    int beg = ip[node], end = ip[node + 1];
    float l = 0.f, a[32];
#pragma unroll
    for (int i = 0; i < 32; ++i) a[i] = 0.f;
    for (int i = beg + sub; i < end; i += 2) {
      int s = csr_r[i];
      float ee = elr[s * 4 + hd] + er_h;
      ee = ee > 0.f ? ee : 0.2f * ee;
      float p = __expf(ee);
      const uint4* fp = (const uint4*)(f + (size_t)s * FDIM);
      uint4 u0 = fp[0], u1 = fp[1], u2 = fp[2], u3 = fp[3];
      l += p;
      unsigned uu[16] = {u0.x, u0.y, u0.z, u0.w, u1.x, u1.y, u1.z, u1.w,
                         u2.x, u2.y, u2.z, u2.w, u3.x, u3.y, u3.z, u3.w};
#pragma unroll
      for (int j = 0; j < 16; ++j) {
        float f0 = __uint_as_float(uu[j] << 16);
        float f1 = __uint_as_float(uu[j] & 0xFFFF0000u);
        a[2 * j]     = fmaf(p, f0, a[2 * j]);
        a[2 * j + 1] = fmaf(p, f1, a[2 * j + 1]);
      }
    }
    l += __shfl_xor(l, 4);
#pragma unroll
    for (int i = 0; i < 32; ++i) a[i] += __shfl_xor(a[i], 4);
    float inv = (l > 0.f) ? 1.f / l : 0.f;
    const float4* b4 = (const float4*)(bias + r * FDIM + hd * DIM);
#pragma unroll
    for (int g = 0; g < 8; ++g) {
      float4 bv = b4[g];
      tot[4 * g]     += a[4 * g] * inv + bv.x;
      tot[4 * g + 1] += a[4 * g + 1] * inv + bv.y;
      tot[4 * g + 2] += a[4 * g + 2] * inv + bv.z;
      tot[4 * g + 3] += a[4 * g + 3] * inv + bv.w;
    }
  }
  {
    const float4* rv4 = (const float4*)(hf + (size_t)node * FDIM + hd * DIM);
#pragma unroll
    for (int g = 0; g < 8; ++g) {
      float4 rv = rv4[g];
      tot[4 * g]     += R * rv.x;
      tot[4 * g + 1] += R * rv.y;
      tot[4 * g + 2] += R * rv.z;
      tot[4 * g + 3] += R * rv.w;
    }
  }
#pragma unroll
  for (int i = 0; i < 32; ++i) {
    float v = tot[i];
    v += __shfl_xor(v, 1);
    v += __shfl_xor(v, 2);
    tot[i] = v * 0.25f;
  }
  if (sub == 0) {
    float4* op = (float4*)(out + (size_t)node * 32 + hd * 8);
    op[0] = make_float4(tot[hd * 8], tot[hd * 8 + 1], tot[hd * 8 + 2], tot[hd * 8 + 3]);
    op[1] = make_float4(tot[hd * 8 + 4], tot[hd * 8 + 5], tot[hd * 8 + 6], tot[hd * 8 + 7]);
  }
}

extern "C" void kernel_launch(void* const* d_in, const int* in_sizes, int n_in,
                              void* d_out, int out_size, void* d_ws, size_t ws_size,
                              hipStream_t stream) {
  const float* x   = (const float*)d_in[0];
  const float* W1  = (const float*)d_in[1];
  const float* al1 = (const float*)d_in[2];
  const float* ar1 = (const float*)d_in[3];
  const float* b1  = (const float*)d_in[4];
  const float* W2  = (const float*)d_in[5];
  const float* al2 = (const float*)d_in[6];
  const float* ar2 = (const float*)d_in[7];
  const float* b2  = (const float*)d_in[8];
  const int* edges = (const int*)d_in[9];
  float* out = (float*)d_out;

  const int N = in_sizes[0] / FDIM;          // 50000 (< 65536: packed binned valid)
  const int R = in_sizes[1] / (FDIM * FDIM); // 2
  const int E = in_sizes[9] / (2 * R);       // 800000
  const int BA = (E + EPB - 1) / EPB;
  const int BAp = (BA + 3) & ~3;
  const int NB = (N + 255) >> BPBSH;

  char* ws = (char*)d_ws;
  size_t off = 0;
  auto alloc = [&](size_t bytes) {
    char* p = ws + off;
    off += (bytes + 255) & ~(size_t)255;
    return p;
  };
  unsigned short* featb = (unsigned short*)alloc((size_t)R * N * FDIM * 2);
  unsigned short* WT    = (unsigned short*)alloc((size_t)2 * R * FDIM * FDIM * 2);
  float* el = (float*)alloc((size_t)R * N * 4 * 4);
  float* er = (float*)alloc((size_t)R * N * 4 * 4);
  float* h  = (float*)alloc((size_t)N * FDIM * 4);
  int* cntA = (int*)alloc((size_t)R * 256 * BAp * 4);
  int* bucketBase = (int*)alloc((size_t)R * 257 * 4);
  unsigned* binned = (unsigned*)alloc((size_t)R * E * 4);   // packed (dst<<16)|src
  int* csr = (int*)alloc((size_t)R * E * 4);
  int* indptr = (int*)alloc((size_t)R * (N + 1) * 4);

  dim3 bgrid(BA + WB, R);
  binA_kernel<<<bgrid, 256, 0, stream>>>(edges, cntA, W1, W2, WT, E, BA, BAp, R);
  scanA_kernel<<<R, 256, 0, stream>>>(cntA, bucketBase, E, NB, BA, BAp);
  dim3 sgrid(BA, R);
  scatterA_kernel<<<sgrid, 256, 0, stream>>>(edges, cntA, binned, E, BA, BAp);
  dim3 pgrid(NB, R);
  passB_kernel<<<pgrid, 256, 0, stream>>>(binned, bucketBase, csr, indptr, E, N, NB);

  dim3 mmgrid((N + 127) / 128, R);
  int agrid = (N * 8 + 255) / 256;

  // ---- layer 1 ----
  mm_kernel<<<mmgrid, 256, 0, stream>>>(x, WT, al1, ar1, featb, el, er, N);
  agg1_kernel<<<agrid, 256, 0, stream>>>(featb, el, er, indptr, csr, b1, h, N, E, R);

  // ---- layer 2 ----
  mm_kernel<<<mmgrid, 256, 0, stream>>>(h, WT + (size_t)R * FDIM * FDIM, al2, ar2, featb, el, er, N);
  agg2_kernel<<<agrid, 256, 0, stream>>>(featb, el, er, indptr, csr, b2, h, out, N, E, R);
}